// Round 3
// baseline (444.278 us; speedup 1.0000x reference)
//
#include <hip/hip_runtime.h>

#define ALP 0.1f          // alpha
#define OMA 0.9f          // 1 - alpha
#define D 64
#define DV 16             // float4 chunks per row

// ---------------- CSR build ----------------

// histogram of dst, int4-vectorized
__global__ void vsgc_hist4(const int4* __restrict__ dst4, int* __restrict__ cnt, int E4) {
    int i = blockIdx.x * blockDim.x + threadIdx.x;
    if (i >= E4) return;
    int4 d = dst4[i];
    atomicAdd(&cnt[d.x], 1);
    atomicAdd(&cnt[d.y], 1);
    atomicAdd(&cnt[d.z], 1);
    atomicAdd(&cnt[d.w], 1);
}
__global__ void vsgc_hist_tail(const int* __restrict__ dst, int* __restrict__ cnt,
                               int begin, int E) {
    int i = begin + blockIdx.x * blockDim.x + threadIdx.x;
    if (i < E) atomicAdd(&cnt[dst[i]], 1);
}

// single-block full exclusive scan: off[] = exscan(cnt), cur[] = off[]
__global__ __launch_bounds__(1024) void vsgc_scan(const int* __restrict__ cnt,
                                                  int* __restrict__ off,
                                                  int* __restrict__ cur, int N) {
    __shared__ int sums[1024];
    int tid = threadIdx.x;
    int per = (N + 1023) >> 10;
    int start = tid * per;
    int end = min(start + per, N);
    int s = 0;
    for (int i = start; i < end; ++i) s += cnt[i];
    sums[tid] = s;
    __syncthreads();
    int v = s;
    for (int d = 1; d < 1024; d <<= 1) {
        int t = (tid >= d) ? sums[tid - d] : 0;
        __syncthreads();
        sums[tid] += t;
        __syncthreads();
    }
    int run = sums[tid] - v;   // exclusive prefix of this thread's chunk
    for (int i = start; i < end; ++i) {
        int c = cnt[i];
        off[i] = run;
        cur[i] = run;
        run += c;
    }
}

// scatter edge records (src, aft_A[src]) into dst-ordered segments, int4-vectorized
__global__ void vsgc_fill4(const int4* __restrict__ src4, const int4* __restrict__ dst4,
                           const float* __restrict__ aft_A,
                           int* __restrict__ cur, int2* __restrict__ edges, int E4) {
    int i = blockIdx.x * blockDim.x + threadIdx.x;
    if (i >= E4) return;
    int4 s = src4[i];
    int4 d = dst4[i];
    int p0 = atomicAdd(&cur[d.x], 1);
    edges[p0] = make_int2(s.x, __float_as_int(aft_A[s.x]));
    int p1 = atomicAdd(&cur[d.y], 1);
    edges[p1] = make_int2(s.y, __float_as_int(aft_A[s.y]));
    int p2 = atomicAdd(&cur[d.z], 1);
    edges[p2] = make_int2(s.z, __float_as_int(aft_A[s.z]));
    int p3 = atomicAdd(&cur[d.w], 1);
    edges[p3] = make_int2(s.w, __float_as_int(aft_A[s.w]));
}
__global__ void vsgc_fill_tail(const int* __restrict__ src, const int* __restrict__ dst,
                               const float* __restrict__ aft_A,
                               int* __restrict__ cur, int2* __restrict__ edges,
                               int begin, int E) {
    int i = begin + blockIdx.x * blockDim.x + threadIdx.x;
    if (i >= E) return;
    int s = src[i];
    int pos = atomicAdd(&cur[dst[i]], 1);
    edges[pos] = make_int2(s, __float_as_int(aft_A[s]));
}

// ---------------- gather + fused epilogue ----------------
// One wave (64 lanes) per node: 4 edge-groups x 16 lanes (float4 each).
// Avg degree 8 -> ~2 serial iterations with 4 row-loads in flight.
__global__ void vsgc_gather(const float4* __restrict__ h4,
                            const float4* __restrict__ ini4,
                            const float* __restrict__ bef_A,
                            const float* __restrict__ bef_X,
                            const int* __restrict__ off,
                            const int* __restrict__ cnt,
                            const int2* __restrict__ edges,
                            float4* __restrict__ out4, int N) {
    int g = (blockIdx.x * blockDim.x + threadIdx.x) >> 6;   // node = wave id
    if (g >= N) return;
    int lane = threadIdx.x & 63;
    int w = lane >> 4;          // edge group 0..3
    int q = lane & 15;          // float4 index within row
    int beg = off[g];           // wave-uniform
    int n = cnt[g];
    float4 acc = make_float4(0.f, 0.f, 0.f, 0.f);
    for (int i = w; i < n; i += 4) {
        int2 rec = edges[beg + i];
        float wt = __int_as_float(rec.y);
        float4 hv = h4[(size_t)rec.x * DV + q];
        acc.x += wt * hv.x;
        acc.y += wt * hv.y;
        acc.z += wt * hv.z;
        acc.w += wt * hv.w;
    }
    // reduce the 4 edge groups (lanes differing in bits 4,5)
    acc.x += __shfl_xor(acc.x, 16); acc.y += __shfl_xor(acc.y, 16);
    acc.z += __shfl_xor(acc.z, 16); acc.w += __shfl_xor(acc.w, 16);
    acc.x += __shfl_xor(acc.x, 32); acc.y += __shfl_xor(acc.y, 32);
    acc.z += __shfl_xor(acc.z, 32); acc.w += __shfl_xor(acc.w, 32);
    if (w == 0) {
        float cb = ALP * bef_A[g];
        float bx = ALP * bef_X[g];
        size_t idx = (size_t)g * DV + q;
        float4 hv = h4[idx];
        float4 iv = ini4[idx];
        float4 o;
        o.x = OMA * hv.x + bx * iv.x + cb * acc.x;
        o.y = OMA * hv.y + bx * iv.y + cb * acc.y;
        o.z = OMA * hv.z + bx * iv.z + cb * acc.z;
        o.w = OMA * hv.w + bx * iv.w + cb * acc.w;
        out4[idx] = o;
    }
}

extern "C" void kernel_launch(void* const* d_in, const int* in_sizes, int n_in,
                              void* d_out, int out_size, void* d_ws, size_t ws_size,
                              hipStream_t stream) {
    const float* h     = (const float*)d_in[0];
    const float* ini_h = (const float*)d_in[1];
    const float* bef_A = (const float*)d_in[2];
    const float* aft_A = (const float*)d_in[3];
    const float* bef_X = (const float*)d_in[4];
    const int*   src   = (const int*)d_in[5];
    const int*   dst   = (const int*)d_in[6];
    float* out = (float*)d_out;

    const int N = in_sizes[0] / D;      // 100000
    const int E = in_sizes[5];          // 800000

    // workspace layout (ints): cnt[N] | off[N] | cur[N] | edges int2[E]
    size_t intWords = (size_t)3 * N;
    size_t intBytes = ((intWords * 4 + 255) / 256) * 256;
    int* cnt = (int*)d_ws;
    int* off = cnt + N;
    int* cur = off + N;
    int2* edges = (int2*)((char*)d_ws + intBytes);

    const int t = 256;

    // zero only cnt
    hipMemsetAsync(cnt, 0, (size_t)N * 4, stream);

    int E4 = E >> 2;
    if (E4 > 0)
        vsgc_hist4<<<(E4 + t - 1) / t, t, 0, stream>>>((const int4*)dst, cnt, E4);
    if (E & 3)
        vsgc_hist_tail<<<1, 64, 0, stream>>>(dst, cnt, E4 << 2, E);

    vsgc_scan<<<1, 1024, 0, stream>>>(cnt, off, cur, N);

    if (E4 > 0)
        vsgc_fill4<<<(E4 + t - 1) / t, t, 0, stream>>>(
            (const int4*)src, (const int4*)dst, aft_A, cur, edges, E4);
    if (E & 3)
        vsgc_fill_tail<<<1, 64, 0, stream>>>(src, dst, aft_A, cur, edges, E4 << 2, E);

    // one wave per node
    long long threadsTotal = (long long)N * 64;
    vsgc_gather<<<(int)((threadsTotal + t - 1) / t), t, 0, stream>>>(
        (const float4*)h, (const float4*)ini_h, bef_A, bef_X,
        off, cnt, edges, (float4*)out, N);
}

// Round 4
// 238.132 us; speedup vs baseline: 1.8657x; 1.8657x over previous
//
#include <hip/hip_runtime.h>

#define ALP 0.1f          // alpha
#define OMA 0.9f          // 1 - alpha
#define D 64
#define DV 16             // float4 chunks per row

// ---------------- CSR build ----------------

// histogram of dst, int4-vectorized (E assumed %4==0; tail kernel otherwise)
__global__ void vsgc_hist4(const int4* __restrict__ dst4, int* __restrict__ cnt, int E4) {
    int i = blockIdx.x * blockDim.x + threadIdx.x;
    if (i >= E4) return;
    int4 d = dst4[i];
    atomicAdd(&cnt[d.x], 1);
    atomicAdd(&cnt[d.y], 1);
    atomicAdd(&cnt[d.z], 1);
    atomicAdd(&cnt[d.w], 1);
}
__global__ void vsgc_hist_tail(const int* __restrict__ dst, int* __restrict__ cnt,
                               int begin, int E) {
    int i = begin + blockIdx.x * blockDim.x + threadIdx.x;
    if (i < E) atomicAdd(&cnt[dst[i]], 1);
}

// scan1: 256 thr/block, 4 elements/thread (int4, coalesced). Writes per-block
// exclusive offsets and the block total.
__global__ __launch_bounds__(256) void vsgc_scan1(const int* __restrict__ cnt,
                                                  int* __restrict__ off,
                                                  int* __restrict__ partial, int N) {
    __shared__ int lds[256];
    int tid = threadIdx.x;
    int base = (blockIdx.x * 256 + tid) * 4;
    int4 v = make_int4(0, 0, 0, 0);
    if (base + 3 < N) {
        v = *(const int4*)(cnt + base);
    } else {
        if (base + 0 < N) v.x = cnt[base + 0];
        if (base + 1 < N) v.y = cnt[base + 1];
        if (base + 2 < N) v.z = cnt[base + 2];
    }
    int s = v.x + v.y + v.z + v.w;
    lds[tid] = s;
    __syncthreads();
    for (int d = 1; d < 256; d <<= 1) {
        int t = (tid >= d) ? lds[tid - d] : 0;
        __syncthreads();
        lds[tid] += t;
        __syncthreads();
    }
    int ex = lds[tid] - s;                 // exclusive prefix of this thread
    if (tid == 255) partial[blockIdx.x] = lds[255];
    int4 o;
    o.x = ex;
    o.y = o.x + v.x;
    o.z = o.y + v.y;
    o.w = o.z + v.z;
    if (base + 3 < N) {
        *(int4*)(off + base) = o;
    } else {
        if (base + 0 < N) off[base + 0] = o.x;
        if (base + 1 < N) off[base + 1] = o.y;
        if (base + 2 < N) off[base + 2] = o.z;
    }
}

// scan2: one 128-thread block scans B (<=128) block totals -> exclusive
__global__ __launch_bounds__(128) void vsgc_scan2(int* __restrict__ partial, int B) {
    __shared__ int lds[128];
    int tid = threadIdx.x;
    int v = (tid < B) ? partial[tid] : 0;
    lds[tid] = v;
    __syncthreads();
    for (int d = 1; d < 128; d <<= 1) {
        int t = (tid >= d) ? lds[tid - d] : 0;
        __syncthreads();
        lds[tid] += t;
        __syncthreads();
    }
    if (tid < B) partial[tid] = lds[tid] - v;   // exclusive
}

// scan3: off += partial[block]; cur = off  (int4 coalesced)
__global__ __launch_bounds__(256) void vsgc_scan3(int* __restrict__ off,
                                                  int* __restrict__ cur,
                                                  const int* __restrict__ partial, int N) {
    int add = partial[blockIdx.x];
    int base = (blockIdx.x * 256 + threadIdx.x) * 4;
    if (base + 3 < N) {
        int4 o = *(const int4*)(off + base);
        o.x += add; o.y += add; o.z += add; o.w += add;
        *(int4*)(off + base) = o;
        *(int4*)(cur + base) = o;
    } else {
        for (int k = 0; k < 4; ++k)
            if (base + k < N) { int o = off[base + k] + add; off[base + k] = o; cur[base + k] = o; }
    }
}

// fill: scatter src index into dst-ordered segments (4B records)
__global__ void vsgc_fill4(const int4* __restrict__ src4, const int4* __restrict__ dst4,
                           int* __restrict__ cur, int* __restrict__ edges, int E4) {
    int i = blockIdx.x * blockDim.x + threadIdx.x;
    if (i >= E4) return;
    int4 s = src4[i];
    int4 d = dst4[i];
    edges[atomicAdd(&cur[d.x], 1)] = s.x;
    edges[atomicAdd(&cur[d.y], 1)] = s.y;
    edges[atomicAdd(&cur[d.z], 1)] = s.z;
    edges[atomicAdd(&cur[d.w], 1)] = s.w;
}
__global__ void vsgc_fill_tail(const int* __restrict__ src, const int* __restrict__ dst,
                               int* __restrict__ cur, int* __restrict__ edges,
                               int begin, int E) {
    int i = begin + blockIdx.x * blockDim.x + threadIdx.x;
    if (i >= E) return;
    edges[atomicAdd(&cur[dst[i]], 1)] = src[i];
}

// ---------------- gather + fused epilogue ----------------
// One wave per node: 4 edge-groups x 16 lanes (float4 each), 2x unrolled
// -> up to 8 h-rows in flight per wave.
__global__ void vsgc_gather(const float4* __restrict__ h4,
                            const float4* __restrict__ ini4,
                            const float* __restrict__ bef_A,
                            const float* __restrict__ bef_X,
                            const float* __restrict__ aft_A,
                            const int* __restrict__ off,
                            const int* __restrict__ cnt,
                            const int* __restrict__ edges,
                            float4* __restrict__ out4, int N) {
    int g = (blockIdx.x * blockDim.x + threadIdx.x) >> 6;   // node = wave id
    if (g >= N) return;
    int lane = threadIdx.x & 63;
    int w = lane >> 4;          // edge group 0..3
    int q = lane & 15;          // float4 index within row
    int beg = off[g];           // wave-uniform
    int n = cnt[g];
    float4 acc = make_float4(0.f, 0.f, 0.f, 0.f);
    for (int i = w; i < n; i += 8) {
        int s0 = edges[beg + i];
        int i1 = i + 4;
        bool has1 = i1 < n;
        int s1 = has1 ? edges[beg + i1] : s0;
        float wt0 = aft_A[s0];
        float4 h0 = h4[(size_t)s0 * DV + q];
        float wt1 = has1 ? aft_A[s1] : 0.f;
        float4 h1 = h4[(size_t)s1 * DV + q];
        acc.x += wt0 * h0.x + wt1 * h1.x;
        acc.y += wt0 * h0.y + wt1 * h1.y;
        acc.z += wt0 * h0.z + wt1 * h1.z;
        acc.w += wt0 * h0.w + wt1 * h1.w;
    }
    acc.x += __shfl_xor(acc.x, 16); acc.y += __shfl_xor(acc.y, 16);
    acc.z += __shfl_xor(acc.z, 16); acc.w += __shfl_xor(acc.w, 16);
    acc.x += __shfl_xor(acc.x, 32); acc.y += __shfl_xor(acc.y, 32);
    acc.z += __shfl_xor(acc.z, 32); acc.w += __shfl_xor(acc.w, 32);
    if (w == 0) {
        float cb = ALP * bef_A[g];
        float bx = ALP * bef_X[g];
        size_t idx = (size_t)g * DV + q;
        float4 hv = h4[idx];
        float4 iv = ini4[idx];
        float4 o;
        o.x = OMA * hv.x + bx * iv.x + cb * acc.x;
        o.y = OMA * hv.y + bx * iv.y + cb * acc.y;
        o.z = OMA * hv.z + bx * iv.z + cb * acc.z;
        o.w = OMA * hv.w + bx * iv.w + cb * acc.w;
        out4[idx] = o;
    }
}

extern "C" void kernel_launch(void* const* d_in, const int* in_sizes, int n_in,
                              void* d_out, int out_size, void* d_ws, size_t ws_size,
                              hipStream_t stream) {
    const float* h     = (const float*)d_in[0];
    const float* ini_h = (const float*)d_in[1];
    const float* bef_A = (const float*)d_in[2];
    const float* aft_A = (const float*)d_in[3];
    const float* bef_X = (const float*)d_in[4];
    const int*   src   = (const int*)d_in[5];
    const int*   dst   = (const int*)d_in[6];
    float* out = (float*)d_out;

    const int N = in_sizes[0] / D;      // 100000
    const int E = in_sizes[5];          // 800000

    // workspace: cnt[N] | off[N] | cur[N] | partial[128] | edges int[E]
    size_t intWords = (size_t)3 * N + 128;
    size_t intBytes = ((intWords * 4 + 255) / 256) * 256;
    int* cnt = (int*)d_ws;
    int* off = cnt + N;
    int* cur = off + N;
    int* partial = cur + N;
    int* edges = (int*)((char*)d_ws + intBytes);

    const int t = 256;

    hipMemsetAsync(cnt, 0, (size_t)N * 4, stream);

    int E4 = E >> 2;
    if (E4 > 0)
        vsgc_hist4<<<(E4 + t - 1) / t, t, 0, stream>>>((const int4*)dst, cnt, E4);
    if (E & 3)
        vsgc_hist_tail<<<1, 64, 0, stream>>>(dst, cnt, E4 << 2, E);

    int B = (N + 1023) >> 10;           // elements per scan1 block = 1024
    vsgc_scan1<<<B, 256, 0, stream>>>(cnt, off, partial, N);
    vsgc_scan2<<<1, 128, 0, stream>>>(partial, B);
    vsgc_scan3<<<B, 256, 0, stream>>>(off, cur, partial, N);

    if (E4 > 0)
        vsgc_fill4<<<(E4 + t - 1) / t, t, 0, stream>>>(
            (const int4*)src, (const int4*)dst, cur, edges, E4);
    if (E & 3)
        vsgc_fill_tail<<<1, 64, 0, stream>>>(src, dst, cur, edges, E4 << 2, E);

    long long threadsTotal = (long long)N * 64;
    vsgc_gather<<<(int)((threadsTotal + t - 1) / t), t, 0, stream>>>(
        (const float4*)h, (const float4*)ini_h, bef_A, bef_X, aft_A,
        off, cnt, edges, (float4*)out, N);
}

// Round 5
// 197.924 us; speedup vs baseline: 2.2447x; 1.2032x over previous
//
#include <hip/hip_runtime.h>

#define ALP 0.1f          // alpha
#define OMA 0.9f          // 1 - alpha
#define D 64
#define DV 16             // float4 chunks per row
#define OVF_MAX 8192      // overflow edge capacity (real data: ~0 used at CAP>=32)

// ---------------- ELL build ----------------
// slot = atomicAdd(cnt[dst]); record src at ell[dst*CAP+slot]. No hist/scan.
__global__ void vsgc_fill_ell(const int* __restrict__ src, const int* __restrict__ dst,
                              int* __restrict__ cnt, int* __restrict__ ell,
                              int2* __restrict__ ovf, int* __restrict__ ovfCnt,
                              int E, int CAP) {
    int i = blockIdx.x * blockDim.x + threadIdx.x;
    if (i >= E) return;
    int s = src[i];
    int d = dst[i];
    int slot = atomicAdd(&cnt[d], 1);
    if (slot < CAP) {
        ell[(size_t)d * CAP + slot] = s;
    } else {
        int p = atomicAdd(ovfCnt, 1);
        if (p < OVF_MAX) ovf[p] = make_int2(s, d);
    }
}

// ---------------- gather + fused epilogue ----------------
// One wave per node: 4 edge-groups x 16 lanes (float4 each), 2x unrolled
// -> up to 8 h-rows in flight per wave.
__global__ void vsgc_gather(const float4* __restrict__ h4,
                            const float4* __restrict__ ini4,
                            const float* __restrict__ bef_A,
                            const float* __restrict__ bef_X,
                            const float* __restrict__ aft_A,
                            const int* __restrict__ cnt,
                            const int* __restrict__ ell,
                            float4* __restrict__ out4, int N, int CAP) {
    int g = (blockIdx.x * blockDim.x + threadIdx.x) >> 6;   // node = wave id
    if (g >= N) return;
    int lane = threadIdx.x & 63;
    int w = lane >> 4;          // edge group 0..3
    int q = lane & 15;          // float4 index within row
    int n = min(cnt[g], CAP);   // wave-uniform
    size_t beg = (size_t)g * CAP;
    float4 acc = make_float4(0.f, 0.f, 0.f, 0.f);
    for (int i = w; i < n; i += 8) {
        int s0 = ell[beg + i];
        int i1 = i + 4;
        bool has1 = i1 < n;
        int s1 = has1 ? ell[beg + i1] : s0;
        float wt0 = aft_A[s0];
        float4 h0 = h4[(size_t)s0 * DV + q];
        float wt1 = has1 ? aft_A[s1] : 0.f;
        float4 h1 = h4[(size_t)s1 * DV + q];
        acc.x += wt0 * h0.x + wt1 * h1.x;
        acc.y += wt0 * h0.y + wt1 * h1.y;
        acc.z += wt0 * h0.z + wt1 * h1.z;
        acc.w += wt0 * h0.w + wt1 * h1.w;
    }
    acc.x += __shfl_xor(acc.x, 16); acc.y += __shfl_xor(acc.y, 16);
    acc.z += __shfl_xor(acc.z, 16); acc.w += __shfl_xor(acc.w, 16);
    acc.x += __shfl_xor(acc.x, 32); acc.y += __shfl_xor(acc.y, 32);
    acc.z += __shfl_xor(acc.z, 32); acc.w += __shfl_xor(acc.w, 32);
    if (w == 0) {
        float cb = ALP * bef_A[g];
        float bx = ALP * bef_X[g];
        size_t idx = (size_t)g * DV + q;
        float4 hv = h4[idx];
        float4 iv = ini4[idx];
        float4 o;
        o.x = OMA * hv.x + bx * iv.x + cb * acc.x;
        o.y = OMA * hv.y + bx * iv.y + cb * acc.y;
        o.z = OMA * hv.z + bx * iv.z + cb * acc.z;
        o.w = OMA * hv.w + bx * iv.w + cb * acc.w;
        out4[idx] = o;
    }
}

// overflow fixup: atomic-add any edges beyond CAP into out (runs after gather)
__global__ void vsgc_ovf(const float4* __restrict__ h4,
                         const float* __restrict__ aft_A,
                         const float* __restrict__ bef_A,
                         const int2* __restrict__ ovf,
                         const int* __restrict__ ovfCnt,
                         float* __restrict__ out) {
    int total = min(*ovfCnt, OVF_MAX);
    int stride = blockDim.x * gridDim.x;
    for (int t = blockIdx.x * blockDim.x + threadIdx.x; t < total * 16; t += stride) {
        int e = t >> 4, q = t & 15;
        int2 r = ovf[e];
        float c = ALP * aft_A[r.x] * bef_A[r.y];
        float4 hv = h4[(size_t)r.x * DV + q];
        float* op = out + (size_t)r.y * D + (q << 2);
        unsafeAtomicAdd(op + 0, c * hv.x);
        unsafeAtomicAdd(op + 1, c * hv.y);
        unsafeAtomicAdd(op + 2, c * hv.z);
        unsafeAtomicAdd(op + 3, c * hv.w);
    }
}

// ---------------- fallback (tiny-workspace atomic path) ----------------
__global__ void vsgc_init(const float4* __restrict__ h,
                          const float4* __restrict__ ini_h,
                          const float* __restrict__ bef_X,
                          float4* __restrict__ out, int n4) {
    int i = blockIdx.x * blockDim.x + threadIdx.x;
    if (i >= n4) return;
    int node = i >> 4;
    float bx = ALP * bef_X[node];
    float4 hv = h[i];
    float4 iv = ini_h[i];
    float4 o;
    o.x = OMA * hv.x + bx * iv.x;
    o.y = OMA * hv.y + bx * iv.y;
    o.z = OMA * hv.z + bx * iv.z;
    o.w = OMA * hv.w + bx * iv.w;
    out[i] = o;
}

__global__ void vsgc_edges_atomic(const float4* __restrict__ h,
                                  const float* __restrict__ aft_A,
                                  const float* __restrict__ bef_A,
                                  const int* __restrict__ src,
                                  const int* __restrict__ dst,
                                  float* __restrict__ out, int E) {
    int tid = blockIdx.x * blockDim.x + threadIdx.x;
    int e = tid >> 4;
    int q = tid & 15;
    if (e >= E) return;
    int s = src[e];
    int d = dst[e];
    float c = ALP * aft_A[s] * bef_A[d];
    float4 hv = h[(size_t)s * DV + q];
    float* op = out + (size_t)d * D + (q << 2);
    unsafeAtomicAdd(op + 0, c * hv.x);
    unsafeAtomicAdd(op + 1, c * hv.y);
    unsafeAtomicAdd(op + 2, c * hv.z);
    unsafeAtomicAdd(op + 3, c * hv.w);
}

extern "C" void kernel_launch(void* const* d_in, const int* in_sizes, int n_in,
                              void* d_out, int out_size, void* d_ws, size_t ws_size,
                              hipStream_t stream) {
    const float* h     = (const float*)d_in[0];
    const float* ini_h = (const float*)d_in[1];
    const float* bef_A = (const float*)d_in[2];
    const float* aft_A = (const float*)d_in[3];
    const float* bef_X = (const float*)d_in[4];
    const int*   src   = (const int*)d_in[5];
    const int*   dst   = (const int*)d_in[6];
    float* out = (float*)d_out;

    const int N = in_sizes[0] / D;      // 100000
    const int E = in_sizes[5];          // 800000
    const int t = 256;

    // ws layout: cnt[N] | ovfCnt[1] | (pad) | ovf int2[OVF_MAX] | ell[N*CAP]
    size_t cntBytes = ((size_t)(N + 1) * 4 + 255) / 256 * 256;
    size_t ellOff = cntBytes + (size_t)OVF_MAX * 8;
    int CAP = 0;
    if (ws_size >= ellOff + (size_t)N * 32 * 4) CAP = 32;
    else if (ws_size >= ellOff + (size_t)N * 16 * 4) CAP = 16;

    if (CAP > 0) {
        int* cnt = (int*)d_ws;
        int* ovfCnt = cnt + N;
        int2* ovf = (int2*)((char*)d_ws + cntBytes);
        int* ell = (int*)((char*)d_ws + ellOff);

        hipMemsetAsync(cnt, 0, (size_t)(N + 1) * 4, stream);

        vsgc_fill_ell<<<(E + t - 1) / t, t, 0, stream>>>(
            src, dst, cnt, ell, ovf, ovfCnt, E, CAP);

        long long threadsTotal = (long long)N * 64;
        vsgc_gather<<<(int)((threadsTotal + t - 1) / t), t, 0, stream>>>(
            (const float4*)h, (const float4*)ini_h, bef_A, bef_X, aft_A,
            cnt, ell, (float4*)out, N, CAP);

        vsgc_ovf<<<64, t, 0, stream>>>(
            (const float4*)h, aft_A, bef_A, ovf, ovfCnt, out);
    } else {
        int n4 = N * DV;
        vsgc_init<<<(n4 + t - 1) / t, t, 0, stream>>>(
            (const float4*)h, (const float4*)ini_h, bef_X, (float4*)out, n4);
        long long total = (long long)E * DV;
        vsgc_edges_atomic<<<(int)((total + t - 1) / t), t, 0, stream>>>(
            (const float4*)h, aft_A, bef_A, src, dst, out, E);
    }
}

// Round 6
// 178.628 us; speedup vs baseline: 2.4872x; 1.1080x over previous
//
#include <hip/hip_runtime.h>

#define ALP 0.1f          // alpha
#define OMA 0.9f          // 1 - alpha
#define D 64
#define DV 16             // float4 chunks per row
#define SH 9              // 512 nodes per bucket
#define NODES_PER_B 512
#define BATCH 4096        // edges per pass-1 block
#define BCAP_MAX 4608     // bucket capacity (compile-time for LDS)
#define OVF_MAX 65536

// ---------- bf16 helpers ----------
__device__ __forceinline__ unsigned short f2b(float f) {      // RNE
    unsigned u = __float_as_uint(f);
    unsigned r = u + 0x7fffu + ((u >> 16) & 1u);
    return (unsigned short)(r >> 16);
}
__device__ __forceinline__ float b2f(unsigned short u) {
    return __uint_as_float(((unsigned)u) << 16);
}

// ---------- msg = bf16(h * aft_A) ----------
__global__ void vsgc_msg(const float4* __restrict__ h4, const float* __restrict__ aft_A,
                         ushort4* __restrict__ msgb, int n16) {
    int i = blockIdx.x * blockDim.x + threadIdx.x;
    if (i >= n16) return;
    float w = aft_A[i >> 4];
    float4 v = h4[i];
    msgb[i] = make_ushort4(f2b(v.x * w), f2b(v.y * w), f2b(v.z * w), f2b(v.w * w));
}

// ---------- pass 1: LDS-staged bucket scatter (merged 64B writes) ----------
__global__ __launch_bounds__(256) void p1_scatter(const int* __restrict__ src,
                                                  const int* __restrict__ dst,
                                                  int* __restrict__ gcnt,
                                                  int2* __restrict__ buckets,
                                                  int2* __restrict__ ovf,
                                                  int* __restrict__ ovfCnt,
                                                  int E, int NB, int BCAP) {
    __shared__ int2 recs[BATCH];
    __shared__ int cnt[256], off[256], pos[256], gbase[256];
    int tid = threadIdx.x;
    int base = blockIdx.x * BATCH;
    cnt[tid] = 0; pos[tid] = 0;
    __syncthreads();
    int  myb[16];
    int2 myr[16];
#pragma unroll
    for (int k = 0; k < 16; ++k) {
        int i = base + k * 256 + tid;
        if (i < E) {
            int2 r = make_int2(src[i], dst[i]);
            myr[k] = r;
            int b = r.y >> SH;
            myb[k] = b;
            atomicAdd(&cnt[b], 1);
        } else myb[k] = -1;
    }
    __syncthreads();
    int v = cnt[tid];
    off[tid] = v;
    __syncthreads();
    for (int d = 1; d < 256; d <<= 1) {
        int t = (tid >= d) ? off[tid - d] : 0;
        __syncthreads();
        off[tid] += t;
        __syncthreads();
    }
    int ex = off[tid] - v;
    off[tid] = ex;                       // exclusive
    if (tid < NB && v > 0) gbase[tid] = atomicAdd(&gcnt[tid], v);
    __syncthreads();
#pragma unroll
    for (int k = 0; k < 16; ++k) {
        int b = myb[k];
        if (b >= 0) {
            int p = off[b] + atomicAdd(&pos[b], 1);
            recs[p] = myr[k];
        }
    }
    __syncthreads();
    int total = min(BATCH, E - base);
    for (int j = tid; j < total; j += 256) {
        int2 r = recs[j];
        int b = r.y >> SH;
        int idx = gbase[b] + (j - off[b]);
        if (idx < BCAP) buckets[(size_t)b * BCAP + idx] = r;
        else { int p = atomicAdd(ovfCnt, 1); if (p < OVF_MAX) ovf[p] = r; }
    }
}

// ---------- scan bucket counts -> bucket bases ----------
__global__ __launch_bounds__(256) void vsgc_scanB(const int* __restrict__ gcnt,
                                                  int* __restrict__ bucketBase,
                                                  int NB, int BCAP) {
    __shared__ int a[256];
    int tid = threadIdx.x;
    int v = (tid < NB) ? min(gcnt[tid], BCAP) : 0;
    a[tid] = v;
    __syncthreads();
    for (int d = 1; d < 256; d <<= 1) {
        int t = (tid >= d) ? a[tid - d] : 0;
        __syncthreads();
        a[tid] += t;
        __syncthreads();
    }
    if (tid < NB) bucketBase[tid] = a[tid] - v;
}

// ---------- pass 2: per-bucket CSR build in LDS, merged sequential writes ----------
__global__ __launch_bounds__(512) void p2_csr(const int2* __restrict__ buckets,
                                              const int* __restrict__ gcnt,
                                              const int* __restrict__ bucketBase,
                                              int* __restrict__ off_g,
                                              int* __restrict__ cnt_g,
                                              int* __restrict__ srcSorted,
                                              int N, int BCAP) {
    __shared__ int ncnt[NODES_PER_B], noff[NODES_PER_B], npos[NODES_PER_B];
    __shared__ int srcbuf[BCAP_MAX];
    int b = blockIdx.x;
    int tid = threadIdx.x;
    int nb = min(gcnt[b], BCAP);
    int base = bucketBase[b];
    ncnt[tid] = 0; npos[tid] = 0;
    __syncthreads();
    for (int i = tid; i < nb; i += 512) {
        int2 r = buckets[(size_t)b * BCAP + i];
        atomicAdd(&ncnt[r.y & (NODES_PER_B - 1)], 1);
    }
    __syncthreads();
    int v = ncnt[tid];
    noff[tid] = v;
    __syncthreads();
    for (int d = 1; d < 512; d <<= 1) {
        int t = (tid >= d) ? noff[tid - d] : 0;
        __syncthreads();
        noff[tid] += t;
        __syncthreads();
    }
    int ex = noff[tid] - v;
    noff[tid] = ex;
    __syncthreads();
    int node = (b << SH) + tid;
    if (node < N) { off_g[node] = base + ex; cnt_g[node] = v; }
    for (int i = tid; i < nb; i += 512) {
        int2 r = buckets[(size_t)b * BCAP + i];
        int l = r.y & (NODES_PER_B - 1);
        int p = noff[l] + atomicAdd(&npos[l], 1);
        srcbuf[p] = r.x;
    }
    __syncthreads();
    for (int i = tid; i < nb; i += 512) srcSorted[base + i] = srcbuf[i];
}

// ---------- gather (bf16 msg) + fused epilogue ----------
__global__ void vsgc_gather_bf16(const ushort4* __restrict__ msgb,
                                 const float4* __restrict__ h4,
                                 const float4* __restrict__ ini4,
                                 const float* __restrict__ bef_A,
                                 const float* __restrict__ bef_X,
                                 const int* __restrict__ off_g,
                                 const int* __restrict__ cnt_g,
                                 const int* __restrict__ srcSorted,
                                 float4* __restrict__ out4, int N) {
    int g = (blockIdx.x * blockDim.x + threadIdx.x) >> 6;
    if (g >= N) return;
    int lane = threadIdx.x & 63;
    int w = lane >> 4;
    int q = lane & 15;
    int beg = off_g[g];
    int n = cnt_g[g];
    float4 acc = make_float4(0.f, 0.f, 0.f, 0.f);
    for (int i = w; i < n; i += 8) {
        int s0 = srcSorted[beg + i];
        int i1 = i + 4;
        bool has1 = i1 < n;
        int s1 = has1 ? srcSorted[beg + i1] : s0;
        ushort4 m0 = msgb[(size_t)s0 * 16 + q];
        ushort4 m1 = msgb[(size_t)s1 * 16 + q];
        float e = has1 ? 1.f : 0.f;
        acc.x += b2f(m0.x) + e * b2f(m1.x);
        acc.y += b2f(m0.y) + e * b2f(m1.y);
        acc.z += b2f(m0.z) + e * b2f(m1.z);
        acc.w += b2f(m0.w) + e * b2f(m1.w);
    }
    acc.x += __shfl_xor(acc.x, 16); acc.y += __shfl_xor(acc.y, 16);
    acc.z += __shfl_xor(acc.z, 16); acc.w += __shfl_xor(acc.w, 16);
    acc.x += __shfl_xor(acc.x, 32); acc.y += __shfl_xor(acc.y, 32);
    acc.z += __shfl_xor(acc.z, 32); acc.w += __shfl_xor(acc.w, 32);
    if (w == 0) {
        float cb = ALP * bef_A[g];
        float bx = ALP * bef_X[g];
        size_t idx = (size_t)g * DV + q;
        float4 hv = h4[idx];
        float4 iv = ini4[idx];
        float4 o;
        o.x = OMA * hv.x + bx * iv.x + cb * acc.x;
        o.y = OMA * hv.y + bx * iv.y + cb * acc.y;
        o.z = OMA * hv.z + bx * iv.z + cb * acc.z;
        o.w = OMA * hv.w + bx * iv.w + cb * acc.w;
        out4[idx] = o;
    }
}

// ---------- gather (fp32, tier B: no msg buffer) ----------
__global__ void vsgc_gather_f32(const float4* __restrict__ h4,
                                const float4* __restrict__ ini4,
                                const float* __restrict__ bef_A,
                                const float* __restrict__ bef_X,
                                const float* __restrict__ aft_A,
                                const int* __restrict__ off_g,
                                const int* __restrict__ cnt_g,
                                const int* __restrict__ srcSorted,
                                float4* __restrict__ out4, int N) {
    int g = (blockIdx.x * blockDim.x + threadIdx.x) >> 6;
    if (g >= N) return;
    int lane = threadIdx.x & 63;
    int w = lane >> 4;
    int q = lane & 15;
    int beg = off_g[g];
    int n = cnt_g[g];
    float4 acc = make_float4(0.f, 0.f, 0.f, 0.f);
    for (int i = w; i < n; i += 8) {
        int s0 = srcSorted[beg + i];
        int i1 = i + 4;
        bool has1 = i1 < n;
        int s1 = has1 ? srcSorted[beg + i1] : s0;
        float wt0 = aft_A[s0];
        float4 h0 = h4[(size_t)s0 * DV + q];
        float wt1 = has1 ? aft_A[s1] : 0.f;
        float4 h1 = h4[(size_t)s1 * DV + q];
        acc.x += wt0 * h0.x + wt1 * h1.x;
        acc.y += wt0 * h0.y + wt1 * h1.y;
        acc.z += wt0 * h0.z + wt1 * h1.z;
        acc.w += wt0 * h0.w + wt1 * h1.w;
    }
    acc.x += __shfl_xor(acc.x, 16); acc.y += __shfl_xor(acc.y, 16);
    acc.z += __shfl_xor(acc.z, 16); acc.w += __shfl_xor(acc.w, 16);
    acc.x += __shfl_xor(acc.x, 32); acc.y += __shfl_xor(acc.y, 32);
    acc.z += __shfl_xor(acc.z, 32); acc.w += __shfl_xor(acc.w, 32);
    if (w == 0) {
        float cb = ALP * bef_A[g];
        float bx = ALP * bef_X[g];
        size_t idx = (size_t)g * DV + q;
        float4 hv = h4[idx];
        float4 iv = ini4[idx];
        float4 o;
        o.x = OMA * hv.x + bx * iv.x + cb * acc.x;
        o.y = OMA * hv.y + bx * iv.y + cb * acc.y;
        o.z = OMA * hv.z + bx * iv.z + cb * acc.z;
        o.w = OMA * hv.w + bx * iv.w + cb * acc.w;
        out4[idx] = o;
    }
}

// ---------- overflow fixup ----------
__global__ void vsgc_ovf(const float4* __restrict__ h4,
                         const float* __restrict__ aft_A,
                         const float* __restrict__ bef_A,
                         const int2* __restrict__ ovf,
                         const int* __restrict__ ovfCnt,
                         float* __restrict__ out) {
    int total = min(*ovfCnt, OVF_MAX);
    int stride = blockDim.x * gridDim.x;
    for (int t = blockIdx.x * blockDim.x + threadIdx.x; t < total * 16; t += stride) {
        int e = t >> 4, q = t & 15;
        int2 r = ovf[e];
        float c = ALP * aft_A[r.x] * bef_A[r.y];
        float4 hv = h4[(size_t)r.x * DV + q];
        float* op = out + (size_t)r.y * D + (q << 2);
        unsafeAtomicAdd(op + 0, c * hv.x);
        unsafeAtomicAdd(op + 1, c * hv.y);
        unsafeAtomicAdd(op + 2, c * hv.z);
        unsafeAtomicAdd(op + 3, c * hv.w);
    }
}

// ---------- last-resort fallback (R1 atomic path) ----------
__global__ void vsgc_init(const float4* __restrict__ h, const float4* __restrict__ ini_h,
                          const float* __restrict__ bef_X, float4* __restrict__ out, int n4) {
    int i = blockIdx.x * blockDim.x + threadIdx.x;
    if (i >= n4) return;
    int node = i >> 4;
    float bx = ALP * bef_X[node];
    float4 hv = h[i];
    float4 iv = ini_h[i];
    float4 o;
    o.x = OMA * hv.x + bx * iv.x;
    o.y = OMA * hv.y + bx * iv.y;
    o.z = OMA * hv.z + bx * iv.z;
    o.w = OMA * hv.w + bx * iv.w;
    out[i] = o;
}
__global__ void vsgc_edges_atomic(const float4* __restrict__ h,
                                  const float* __restrict__ aft_A,
                                  const float* __restrict__ bef_A,
                                  const int* __restrict__ src,
                                  const int* __restrict__ dst,
                                  float* __restrict__ out, int E) {
    int tid = blockIdx.x * blockDim.x + threadIdx.x;
    int e = tid >> 4;
    int q = tid & 15;
    if (e >= E) return;
    int s = src[e];
    int d = dst[e];
    float c = ALP * aft_A[s] * bef_A[d];
    float4 hv = h[(size_t)s * DV + q];
    float* op = out + (size_t)d * D + (q << 2);
    unsafeAtomicAdd(op + 0, c * hv.x);
    unsafeAtomicAdd(op + 1, c * hv.y);
    unsafeAtomicAdd(op + 2, c * hv.z);
    unsafeAtomicAdd(op + 3, c * hv.w);
}

extern "C" void kernel_launch(void* const* d_in, const int* in_sizes, int n_in,
                              void* d_out, int out_size, void* d_ws, size_t ws_size,
                              hipStream_t stream) {
    const float* h     = (const float*)d_in[0];
    const float* ini_h = (const float*)d_in[1];
    const float* bef_A = (const float*)d_in[2];
    const float* aft_A = (const float*)d_in[3];
    const float* bef_X = (const float*)d_in[4];
    const int*   src   = (const int*)d_in[5];
    const int*   dst   = (const int*)d_in[6];
    float* out = (float*)d_out;

    const int N = in_sizes[0] / D;      // 100000
    const int E = in_sizes[5];          // 800000
    const int t = 256;

    int NB = (N + NODES_PER_B - 1) >> SH;
    int m = (NB > 0) ? E / NB : 0;
    int BCAP = m + m / 2 + 128;
    if (BCAP > BCAP_MAX) BCAP = BCAP_MAX;

    // ws layout (all 256B aligned):
    // gcnt[256] | ovfCnt[64] | bucketBase[256] | ovf int2[OVF_MAX]
    // | off_g[N] | cnt_g[N] | srcSorted[E] | buckets int2[NB*BCAP] | msgb ushort[N*64]
    size_t o_gcnt   = 0;
    size_t o_ovfc   = o_gcnt + 256 * 4;
    size_t o_bbase  = o_ovfc + 64 * 4;
    size_t o_ovf    = ((o_bbase + 256 * 4 + 255) / 256) * 256;
    size_t o_off    = o_ovf + (size_t)OVF_MAX * 8;
    size_t o_cnt    = o_off + (size_t)N * 4;
    size_t o_srcs   = o_cnt + (size_t)N * 4;
    size_t o_bkt    = ((o_srcs + (size_t)E * 4 + 255) / 256) * 256;
    size_t o_msg    = ((o_bkt + (size_t)NB * BCAP * 8 + 255) / 256) * 256;
    size_t needB = o_msg;
    size_t needA = o_msg + (size_t)N * 128;

    if (NB <= 256 && ws_size >= needB) {
        int*  gcnt  = (int*)((char*)d_ws + o_gcnt);
        int*  ovfC  = (int*)((char*)d_ws + o_ovfc);
        int*  bbase = (int*)((char*)d_ws + o_bbase);
        int2* ovf   = (int2*)((char*)d_ws + o_ovf);
        int*  off_g = (int*)((char*)d_ws + o_off);
        int*  cnt_g = (int*)((char*)d_ws + o_cnt);
        int*  srcS  = (int*)((char*)d_ws + o_srcs);
        int2* bkt   = (int2*)((char*)d_ws + o_bkt);
        ushort4* msgb = (ushort4*)((char*)d_ws + o_msg);
        bool tierA = (ws_size >= needA);

        hipMemsetAsync(d_ws, 0, o_bbase, stream);   // gcnt + ovfCnt

        if (tierA) {
            int n16 = N * DV;
            vsgc_msg<<<(n16 + t - 1) / t, t, 0, stream>>>(
                (const float4*)h, aft_A, msgb, n16);
        }

        int p1blocks = (E + BATCH - 1) / BATCH;
        p1_scatter<<<p1blocks, 256, 0, stream>>>(src, dst, gcnt, bkt, ovf, ovfC, E, NB, BCAP);
        vsgc_scanB<<<1, 256, 0, stream>>>(gcnt, bbase, NB, BCAP);
        p2_csr<<<NB, 512, 0, stream>>>(bkt, gcnt, bbase, off_g, cnt_g, srcS, N, BCAP);

        long long threadsTotal = (long long)N * 64;
        int gblocks = (int)((threadsTotal + t - 1) / t);
        if (tierA)
            vsgc_gather_bf16<<<gblocks, t, 0, stream>>>(
                msgb, (const float4*)h, (const float4*)ini_h, bef_A, bef_X,
                off_g, cnt_g, srcS, (float4*)out, N);
        else
            vsgc_gather_f32<<<gblocks, t, 0, stream>>>(
                (const float4*)h, (const float4*)ini_h, bef_A, bef_X, aft_A,
                off_g, cnt_g, srcS, (float4*)out, N);

        vsgc_ovf<<<64, t, 0, stream>>>((const float4*)h, aft_A, bef_A, ovf, ovfC, out);
    } else {
        int n4 = N * DV;
        vsgc_init<<<(n4 + t - 1) / t, t, 0, stream>>>(
            (const float4*)h, (const float4*)ini_h, bef_X, (float4*)out, n4);
        long long total = (long long)E * DV;
        vsgc_edges_atomic<<<(int)((total + t - 1) / t), t, 0, stream>>>(
            (const float4*)h, aft_A, bef_A, src, dst, out, E);
    }
}

// Round 7
// 168.433 us; speedup vs baseline: 2.6377x; 1.0605x over previous
//
#include <hip/hip_runtime.h>

#define ALP 0.1f          // alpha
#define OMA 0.9f          // 1 - alpha
#define D 64
#define DV 16             // float4 chunks per row
#define SH 9              // 512 nodes per bucket
#define NODES_PER_B 512
#define CAP 16            // ELL slots per node (deg>16 -> overflow fixup)
#define OVF_MAX 65536

// ---------- bf16 helpers ----------
__device__ __forceinline__ unsigned short f2b(float f) {      // RNE
    unsigned u = __float_as_uint(f);
    unsigned r = u + 0x7fffu + ((u >> 16) & 1u);
    return (unsigned short)(r >> 16);
}
__device__ __forceinline__ float b2f(unsigned short u) {
    return __uint_as_float(((unsigned)u) << 16);
}

// ---------- msg = bf16(h * aft_A) ----------
__global__ void vsgc_msg(const float4* __restrict__ h4, const float* __restrict__ aft_A,
                         ushort4* __restrict__ msgb, int n16) {
    int i = blockIdx.x * blockDim.x + threadIdx.x;
    if (i >= n16) return;
    float w = aft_A[i >> 4];
    float4 v = h4[i];
    msgb[i] = make_ushort4(f2b(v.x * w), f2b(v.y * w), f2b(v.z * w), f2b(v.w * w));
}

// ---------- pass 1: bucket scatter, packed 4B records, no LDS staging ----------
// 2048 edges/block. Count in LDS -> reserve global range per bucket -> direct
// writes (block's per-bucket range is tiny and L2-resident -> lines merge).
__global__ __launch_bounds__(256) void p1_scatter(const int4* __restrict__ src4,
                                                  const int4* __restrict__ dst4,
                                                  int* __restrict__ gcnt,
                                                  int* __restrict__ buckets,
                                                  int2* __restrict__ ovf,
                                                  int* __restrict__ ovfCnt,
                                                  int E, int NB, int BCAP) {
    __shared__ int cnt[256], gbase[256], pos[256];
    int tid = threadIdx.x;
    cnt[tid] = 0; pos[tid] = 0;
    __syncthreads();
    int nInt4 = (E + 3) >> 2;
    int i0 = blockIdx.x * 512 + tid;
    int i1 = i0 + 256;
    bool v0 = i0 < nInt4, v1 = i1 < nInt4;
    int4 s0 = make_int4(0,0,0,0), d0 = s0, s1 = s0, d1 = s0;
    if (v0) { s0 = src4[i0]; d0 = dst4[i0]; }
    if (v1) { s1 = src4[i1]; d1 = dst4[i1]; }
    int e0 = i0 << 2, e1 = i1 << 2;
    if (v0) {
        if (e0 + 0 < E) atomicAdd(&cnt[d0.x >> SH], 1);
        if (e0 + 1 < E) atomicAdd(&cnt[d0.y >> SH], 1);
        if (e0 + 2 < E) atomicAdd(&cnt[d0.z >> SH], 1);
        if (e0 + 3 < E) atomicAdd(&cnt[d0.w >> SH], 1);
    }
    if (v1) {
        if (e1 + 0 < E) atomicAdd(&cnt[d1.x >> SH], 1);
        if (e1 + 1 < E) atomicAdd(&cnt[d1.y >> SH], 1);
        if (e1 + 2 < E) atomicAdd(&cnt[d1.z >> SH], 1);
        if (e1 + 3 < E) atomicAdd(&cnt[d1.w >> SH], 1);
    }
    __syncthreads();
    if (tid < NB && cnt[tid] > 0) gbase[tid] = atomicAdd(&gcnt[tid], cnt[tid]);
    __syncthreads();
#define EMIT(ss, dd, ok)                                                        \
    if (ok) {                                                                   \
        int b = (dd) >> SH;                                                     \
        int p = gbase[b] + atomicAdd(&pos[b], 1);                               \
        int pkt = ((ss) << SH) | ((dd) & (NODES_PER_B - 1));                    \
        if (p < BCAP) buckets[(size_t)b * BCAP + p] = pkt;                      \
        else { int o = atomicAdd(ovfCnt, 1); if (o < OVF_MAX) ovf[o] = make_int2(ss, dd); } \
    }
    EMIT(s0.x, d0.x, v0 && e0 + 0 < E)
    EMIT(s0.y, d0.y, v0 && e0 + 1 < E)
    EMIT(s0.z, d0.z, v0 && e0 + 2 < E)
    EMIT(s0.w, d0.w, v0 && e0 + 3 < E)
    EMIT(s1.x, d1.x, v1 && e1 + 0 < E)
    EMIT(s1.y, d1.y, v1 && e1 + 1 < E)
    EMIT(s1.z, d1.z, v1 && e1 + 2 < E)
    EMIT(s1.w, d1.w, v1 && e1 + 3 < E)
#undef EMIT
}

// ---------- pass 2: bucket records -> node-local ELL (single pass) ----------
__global__ __launch_bounds__(512) void p2_ell(const int* __restrict__ buckets,
                                              const int* __restrict__ gcnt,
                                              int* __restrict__ ell,
                                              int* __restrict__ cnt_g,
                                              int2* __restrict__ ovf,
                                              int* __restrict__ ovfCnt,
                                              int N, int BCAP) {
    __shared__ int npos[NODES_PER_B];
    int b = blockIdx.x, tid = threadIdx.x;
    npos[tid] = 0;
    __syncthreads();
    int nb = min(gcnt[b], BCAP);
    const int* bp = buckets + (size_t)b * BCAP;
    for (int i = tid; i < nb; i += 512) {
        int pkt = bp[i];
        int l = pkt & (NODES_PER_B - 1);
        int s = (int)(((unsigned)pkt) >> SH);
        int slot = atomicAdd(&npos[l], 1);
        int node = (b << SH) + l;
        if (slot < CAP) ell[(size_t)node * CAP + slot] = s;
        else { int o = atomicAdd(ovfCnt, 1); if (o < OVF_MAX) ovf[o] = make_int2(s, node); }
    }
    __syncthreads();
    int node = (b << SH) + tid;
    if (node < N) cnt_g[node] = npos[tid];
}

// ---------- gather: static ELL addresses -> 2 serial round trips ----------
__global__ __launch_bounds__(256) void vsgc_gather_ell(const ushort4* __restrict__ msgb,
                                                       const float4* __restrict__ h4,
                                                       const float4* __restrict__ ini4,
                                                       const float* __restrict__ bef_A,
                                                       const float* __restrict__ bef_X,
                                                       const int* __restrict__ cnt_g,
                                                       const int* __restrict__ ell,
                                                       float4* __restrict__ out4, int N) {
    int g = (blockIdx.x * blockDim.x + threadIdx.x) >> 6;
    if (g >= N) return;
    int lane = threadIdx.x & 63;
    int w = lane >> 4;          // edge group 0..3
    int q = lane & 15;          // float4/ushort4 index within row
    int ev = ell[(size_t)g * CAP + q];     // coalesced 64B row (slots 0..15)
    int n = min(cnt_g[g], CAP);            // parallel with msg chain
    float4 acc = make_float4(0.f, 0.f, 0.f, 0.f);
#pragma unroll
    for (int k = 0; k < 4; ++k) {
        int idx = w + 4 * k;               // uniform within 16-lane group
        int s = __shfl(ev, idx);           // broadcast from lane idx (<16)
        if (idx < n) {
            ushort4 m = msgb[(size_t)s * DV + q];
            acc.x += b2f(m.x);
            acc.y += b2f(m.y);
            acc.z += b2f(m.z);
            acc.w += b2f(m.w);
        }
    }
    acc.x += __shfl_xor(acc.x, 16); acc.y += __shfl_xor(acc.y, 16);
    acc.z += __shfl_xor(acc.z, 16); acc.w += __shfl_xor(acc.w, 16);
    acc.x += __shfl_xor(acc.x, 32); acc.y += __shfl_xor(acc.y, 32);
    acc.z += __shfl_xor(acc.z, 32); acc.w += __shfl_xor(acc.w, 32);
    if (w == 0) {
        float cb = ALP * bef_A[g];
        float bx = ALP * bef_X[g];
        size_t idx = (size_t)g * DV + q;
        float4 hv = h4[idx];
        float4 iv = ini4[idx];
        float4 o;
        o.x = OMA * hv.x + bx * iv.x + cb * acc.x;
        o.y = OMA * hv.y + bx * iv.y + cb * acc.y;
        o.z = OMA * hv.z + bx * iv.z + cb * acc.z;
        o.w = OMA * hv.w + bx * iv.w + cb * acc.w;
        out4[idx] = o;
    }
}

// ---------- overflow fixup (bucket or ELL slot overflow; fp32 exact) ----------
__global__ void vsgc_ovf(const float4* __restrict__ h4,
                         const float* __restrict__ aft_A,
                         const float* __restrict__ bef_A,
                         const int2* __restrict__ ovf,
                         const int* __restrict__ ovfCnt,
                         float* __restrict__ out) {
    int total = min(*ovfCnt, OVF_MAX);
    int stride = blockDim.x * gridDim.x;
    for (int t = blockIdx.x * blockDim.x + threadIdx.x; t < total * 16; t += stride) {
        int e = t >> 4, q = t & 15;
        int2 r = ovf[e];
        float c = ALP * aft_A[r.x] * bef_A[r.y];
        float4 hv = h4[(size_t)r.x * DV + q];
        float* op = out + (size_t)r.y * D + (q << 2);
        unsafeAtomicAdd(op + 0, c * hv.x);
        unsafeAtomicAdd(op + 1, c * hv.y);
        unsafeAtomicAdd(op + 2, c * hv.z);
        unsafeAtomicAdd(op + 3, c * hv.w);
    }
}

// ---------- last-resort fallback (R1 atomic path) ----------
__global__ void vsgc_init(const float4* __restrict__ h, const float4* __restrict__ ini_h,
                          const float* __restrict__ bef_X, float4* __restrict__ out, int n4) {
    int i = blockIdx.x * blockDim.x + threadIdx.x;
    if (i >= n4) return;
    int node = i >> 4;
    float bx = ALP * bef_X[node];
    float4 hv = h[i];
    float4 iv = ini_h[i];
    float4 o;
    o.x = OMA * hv.x + bx * iv.x;
    o.y = OMA * hv.y + bx * iv.y;
    o.z = OMA * hv.z + bx * iv.z;
    o.w = OMA * hv.w + bx * iv.w;
    out[i] = o;
}
__global__ void vsgc_edges_atomic(const float4* __restrict__ h,
                                  const float* __restrict__ aft_A,
                                  const float* __restrict__ bef_A,
                                  const int* __restrict__ src,
                                  const int* __restrict__ dst,
                                  float* __restrict__ out, int E) {
    int tid = blockIdx.x * blockDim.x + threadIdx.x;
    int e = tid >> 4;
    int q = tid & 15;
    if (e >= E) return;
    int s = src[e];
    int d = dst[e];
    float c = ALP * aft_A[s] * bef_A[d];
    float4 hv = h[(size_t)s * DV + q];
    float* op = out + (size_t)d * D + (q << 2);
    unsafeAtomicAdd(op + 0, c * hv.x);
    unsafeAtomicAdd(op + 1, c * hv.y);
    unsafeAtomicAdd(op + 2, c * hv.z);
    unsafeAtomicAdd(op + 3, c * hv.w);
}

extern "C" void kernel_launch(void* const* d_in, const int* in_sizes, int n_in,
                              void* d_out, int out_size, void* d_ws, size_t ws_size,
                              hipStream_t stream) {
    const float* h     = (const float*)d_in[0];
    const float* ini_h = (const float*)d_in[1];
    const float* bef_A = (const float*)d_in[2];
    const float* aft_A = (const float*)d_in[3];
    const float* bef_X = (const float*)d_in[4];
    const int*   src   = (const int*)d_in[5];
    const int*   dst   = (const int*)d_in[6];
    float* out = (float*)d_out;

    const int N = in_sizes[0] / D;      // 100000
    const int E = in_sizes[5];          // 800000
    const int t = 256;

    int NB = (N + NODES_PER_B - 1) >> SH;
    int perB = (NB > 0) ? E / NB : 0;
    int BCAP = perB + perB / 4 + 256;

    // ws layout (256B aligned regions):
    // gcnt[256] | ovfCnt[64] | ovf int2[OVF_MAX] | cnt_g[N] | ell[N*CAP]
    // | buckets[NB*BCAP] | msgb ushort[N*64]
    size_t o_gcnt = 0;
    size_t o_ovfc = 256 * 4;
    size_t o_ovf  = ((o_ovfc + 64 * 4 + 255) / 256) * 256;
    size_t o_cnt  = o_ovf + (size_t)OVF_MAX * 8;
    size_t o_ell  = ((o_cnt + (size_t)N * 4 + 255) / 256) * 256;
    size_t o_bkt  = ((o_ell + (size_t)N * CAP * 4 + 255) / 256) * 256;
    size_t o_msg  = ((o_bkt + (size_t)NB * BCAP * 4 + 255) / 256) * 256;
    size_t need   = o_msg + (size_t)N * 128;

    // pack needs src in 32-SH bits and NB<=256
    if (NB <= 256 && N <= (1 << (31 - SH)) && ws_size >= need) {
        int*  gcnt  = (int*)((char*)d_ws + o_gcnt);
        int*  ovfC  = (int*)((char*)d_ws + o_ovfc);
        int2* ovf   = (int2*)((char*)d_ws + o_ovf);
        int*  cnt_g = (int*)((char*)d_ws + o_cnt);
        int*  ell   = (int*)((char*)d_ws + o_ell);
        int*  bkt   = (int*)((char*)d_ws + o_bkt);
        ushort4* msgb = (ushort4*)((char*)d_ws + o_msg);

        hipMemsetAsync(d_ws, 0, o_ovf, stream);    // gcnt + ovfCnt

        int n16 = N * DV;
        vsgc_msg<<<(n16 + t - 1) / t, t, 0, stream>>>((const float4*)h, aft_A, msgb, n16);

        int nInt4 = (E + 3) >> 2;
        int p1blocks = (nInt4 + 511) / 512;
        p1_scatter<<<p1blocks, 256, 0, stream>>>(
            (const int4*)src, (const int4*)dst, gcnt, bkt, ovf, ovfC, E, NB, BCAP);

        p2_ell<<<NB, 512, 0, stream>>>(bkt, gcnt, ell, cnt_g, ovf, ovfC, N, BCAP);

        long long threadsTotal = (long long)N * 64;
        vsgc_gather_ell<<<(int)((threadsTotal + t - 1) / t), t, 0, stream>>>(
            msgb, (const float4*)h, (const float4*)ini_h, bef_A, bef_X,
            cnt_g, ell, (float4*)out, N);

        vsgc_ovf<<<64, t, 0, stream>>>((const float4*)h, aft_A, bef_A, ovf, ovfC, out);
    } else {
        int n4 = N * DV;
        vsgc_init<<<(n4 + t - 1) / t, t, 0, stream>>>(
            (const float4*)h, (const float4*)ini_h, bef_X, (float4*)out, n4);
        long long total = (long long)E * DV;
        vsgc_edges_atomic<<<(int)((total + t - 1) / t), t, 0, stream>>>(
            (const float4*)h, aft_A, bef_A, src, dst, out, E);
    }
}

// Round 8
// 162.504 us; speedup vs baseline: 2.7340x; 1.0365x over previous
//
#include <hip/hip_runtime.h>

#define ALP 0.1f          // alpha
#define OMA 0.9f          // 1 - alpha
#define D 64
#define DV 16             // float4 chunks per row
#define SH 9              // 512 nodes per bucket
#define NODES_PER_B 512
#define CAP 16            // ELL slots per node (deg>16 -> overflow fixup)
#define OVF_MAX 65536

// ---------- bf16 helpers ----------
__device__ __forceinline__ unsigned short f2b(float f) {      // RNE
    unsigned u = __float_as_uint(f);
    unsigned r = u + 0x7fffu + ((u >> 16) & 1u);
    return (unsigned short)(r >> 16);
}
__device__ __forceinline__ float b2f(unsigned short u) {
    return __uint_as_float(((unsigned)u) << 16);
}

// ---------- msg = bf16(h * aft_A)  + zero gcnt/ovfCnt (block 0) ----------
__global__ void vsgc_msg(const float4* __restrict__ h4, const float* __restrict__ aft_A,
                         ushort4* __restrict__ msgb, int* __restrict__ zeroRegion,
                         int zeroWords, int n16) {
    if (blockIdx.x == 0) {
        for (int j = threadIdx.x; j < zeroWords; j += blockDim.x) zeroRegion[j] = 0;
    }
    int i = blockIdx.x * blockDim.x + threadIdx.x;
    if (i >= n16) return;
    float w = aft_A[i >> 4];
    float4 v = h4[i];
    msgb[i] = make_ushort4(f2b(v.x * w), f2b(v.y * w), f2b(v.z * w), f2b(v.w * w));
}

// ---------- pass 1: bucket scatter, packed 4B records, phase-split ----------
__global__ __launch_bounds__(256) void p1_scatter(const int4* __restrict__ src4,
                                                  const int4* __restrict__ dst4,
                                                  int* __restrict__ gcnt,
                                                  int* __restrict__ buckets,
                                                  int2* __restrict__ ovf,
                                                  int* __restrict__ ovfCnt,
                                                  int E, int NB, int BCAP) {
    __shared__ int cnt[256], gbase[256], pos[256];
    int tid = threadIdx.x;
    cnt[tid] = 0; pos[tid] = 0;
    __syncthreads();
    int nInt4 = (E + 3) >> 2;
    int i0 = blockIdx.x * 512 + tid;
    int i1 = i0 + 256;
    bool v0 = i0 < nInt4, v1 = i1 < nInt4;
    int4 s0 = make_int4(0,0,0,0), d0 = s0, s1 = s0, d1 = s0;
    if (v0) { s0 = src4[i0]; d0 = dst4[i0]; }
    if (v1) { s1 = src4[i1]; d1 = dst4[i1]; }
    int e0 = i0 << 2, e1 = i1 << 2;
    int ss[8] = {s0.x, s0.y, s0.z, s0.w, s1.x, s1.y, s1.z, s1.w};
    int dd[8] = {d0.x, d0.y, d0.z, d0.w, d1.x, d1.y, d1.z, d1.w};
    bool ok[8];
#pragma unroll
    for (int k = 0; k < 4; ++k) { ok[k] = v0 && (e0 + k < E); ok[4 + k] = v1 && (e1 + k < E); }
#pragma unroll
    for (int k = 0; k < 8; ++k) if (ok[k]) atomicAdd(&cnt[dd[k] >> SH], 1);
    __syncthreads();
    if (tid < NB && cnt[tid] > 0) gbase[tid] = atomicAdd(&gcnt[tid], cnt[tid]);
    __syncthreads();
    // phase A: all slot reservations (independent LDS atomics, pipeline)
    int pp[8];
#pragma unroll
    for (int k = 0; k < 8; ++k)
        pp[k] = ok[k] ? (gbase[dd[k] >> SH] + atomicAdd(&pos[dd[k] >> SH], 1)) : 0;
    // phase B: all stores (independent)
#pragma unroll
    for (int k = 0; k < 8; ++k) {
        if (!ok[k]) continue;
        int b = dd[k] >> SH;
        int pkt = (ss[k] << SH) | (dd[k] & (NODES_PER_B - 1));
        if (pp[k] < BCAP) buckets[(size_t)b * BCAP + pp[k]] = pkt;
        else { int o = atomicAdd(ovfCnt, 1); if (o < OVF_MAX) ovf[o] = make_int2(ss[k], dd[k]); }
    }
}

// ---------- pass 2: bucket records -> node-local ELL (int4 reads) ----------
__global__ __launch_bounds__(512) void p2_ell(const int* __restrict__ buckets,
                                              const int* __restrict__ gcnt,
                                              int* __restrict__ ell,
                                              int* __restrict__ cnt_g,
                                              int2* __restrict__ ovf,
                                              int* __restrict__ ovfCnt,
                                              int N, int BCAP) {
    __shared__ int npos[NODES_PER_B];
    int b = blockIdx.x, tid = threadIdx.x;
    npos[tid] = 0;
    __syncthreads();
    int nb = min(gcnt[b], BCAP);
    const int4* bp4 = (const int4*)(buckets + (size_t)b * BCAP);
    int nIter = (nb + 3) >> 2;
    for (int i4 = tid; i4 < nIter; i4 += 512) {
        int4 r4 = bp4[i4];
        int base = i4 << 2;
        int pk[4] = {r4.x, r4.y, r4.z, r4.w};
#pragma unroll
        for (int k = 0; k < 4; ++k) {
            if (base + k >= nb) break;
            int pkt = pk[k];
            int l = pkt & (NODES_PER_B - 1);
            int s = (int)(((unsigned)pkt) >> SH);
            int slot = atomicAdd(&npos[l], 1);
            int node = (b << SH) + l;
            if (slot < CAP) ell[(size_t)node * CAP + slot] = s;
            else { int o = atomicAdd(ovfCnt, 1); if (o < OVF_MAX) ovf[o] = make_int2(s, node); }
        }
    }
    __syncthreads();
    int node = (b << SH) + tid;
    if (node < N) cnt_g[node] = npos[tid];
}

// ---------- gather: static ELL addresses, unconditional clamped loads ----------
__global__ __launch_bounds__(256) void vsgc_gather_ell(const ushort4* __restrict__ msgb,
                                                       const float4* __restrict__ h4,
                                                       const float4* __restrict__ ini4,
                                                       const float* __restrict__ bef_A,
                                                       const float* __restrict__ bef_X,
                                                       const int* __restrict__ cnt_g,
                                                       const int* __restrict__ ell,
                                                       float4* __restrict__ out4, int N) {
    int g = (blockIdx.x * blockDim.x + threadIdx.x) >> 6;
    if (g >= N) return;
    int lane = threadIdx.x & 63;
    int w = lane >> 4;          // edge group 0..3
    int q = lane & 15;          // float4/ushort4 index within row
    size_t ridx = (size_t)g * DV + q;
    // issue all independent loads up front
    int ev = ell[(size_t)g * CAP + q];     // coalesced 64B row
    int n = min(cnt_g[g], CAP);
    float4 hv = h4[ridx];
    float4 iv = ini4[ridx];
    float cb = ALP * bef_A[g];
    float bx = ALP * bef_X[g];
    float4 acc = make_float4(0.f, 0.f, 0.f, 0.f);
#pragma unroll
    for (int k = 0; k < 4; ++k) {
        int idx = w + 4 * k;               // uniform within 16-lane group
        int s = __shfl(ev, idx);           // broadcast from lane idx (<16)
        unsigned su = min((unsigned)s, (unsigned)(N - 1));   // clamp garbage slots
        float m = (idx < n) ? 1.f : 0.f;
        ushort4 mm = msgb[(size_t)su * DV + q];
        acc.x += m * b2f(mm.x);
        acc.y += m * b2f(mm.y);
        acc.z += m * b2f(mm.z);
        acc.w += m * b2f(mm.w);
    }
    acc.x += __shfl_xor(acc.x, 16); acc.y += __shfl_xor(acc.y, 16);
    acc.z += __shfl_xor(acc.z, 16); acc.w += __shfl_xor(acc.w, 16);
    acc.x += __shfl_xor(acc.x, 32); acc.y += __shfl_xor(acc.y, 32);
    acc.z += __shfl_xor(acc.z, 32); acc.w += __shfl_xor(acc.w, 32);
    if (w == 0) {
        float4 o;
        o.x = OMA * hv.x + bx * iv.x + cb * acc.x;
        o.y = OMA * hv.y + bx * iv.y + cb * acc.y;
        o.z = OMA * hv.z + bx * iv.z + cb * acc.z;
        o.w = OMA * hv.w + bx * iv.w + cb * acc.w;
        out4[ridx] = o;
    }
}

// ---------- overflow fixup (fp32 exact) ----------
__global__ void vsgc_ovf(const float4* __restrict__ h4,
                         const float* __restrict__ aft_A,
                         const float* __restrict__ bef_A,
                         const int2* __restrict__ ovf,
                         const int* __restrict__ ovfCnt,
                         float* __restrict__ out) {
    int total = min(*ovfCnt, OVF_MAX);
    int stride = blockDim.x * gridDim.x;
    for (int t = blockIdx.x * blockDim.x + threadIdx.x; t < total * 16; t += stride) {
        int e = t >> 4, q = t & 15;
        int2 r = ovf[e];
        float c = ALP * aft_A[r.x] * bef_A[r.y];
        float4 hv = h4[(size_t)r.x * DV + q];
        float* op = out + (size_t)r.y * D + (q << 2);
        unsafeAtomicAdd(op + 0, c * hv.x);
        unsafeAtomicAdd(op + 1, c * hv.y);
        unsafeAtomicAdd(op + 2, c * hv.z);
        unsafeAtomicAdd(op + 3, c * hv.w);
    }
}

// ---------- last-resort fallback (R1 atomic path) ----------
__global__ void vsgc_init(const float4* __restrict__ h, const float4* __restrict__ ini_h,
                          const float* __restrict__ bef_X, float4* __restrict__ out, int n4) {
    int i = blockIdx.x * blockDim.x + threadIdx.x;
    if (i >= n4) return;
    int node = i >> 4;
    float bx = ALP * bef_X[node];
    float4 hv = h[i];
    float4 iv = ini_h[i];
    float4 o;
    o.x = OMA * hv.x + bx * iv.x;
    o.y = OMA * hv.y + bx * iv.y;
    o.z = OMA * hv.z + bx * iv.z;
    o.w = OMA * hv.w + bx * iv.w;
    out[i] = o;
}
__global__ void vsgc_edges_atomic(const float4* __restrict__ h,
                                  const float* __restrict__ aft_A,
                                  const float* __restrict__ bef_A,
                                  const int* __restrict__ src,
                                  const int* __restrict__ dst,
                                  float* __restrict__ out, int E) {
    int tid = blockIdx.x * blockDim.x + threadIdx.x;
    int e = tid >> 4;
    int q = tid & 15;
    if (e >= E) return;
    int s = src[e];
    int d = dst[e];
    float c = ALP * aft_A[s] * bef_A[d];
    float4 hv = h[(size_t)s * DV + q];
    float* op = out + (size_t)d * D + (q << 2);
    unsafeAtomicAdd(op + 0, c * hv.x);
    unsafeAtomicAdd(op + 1, c * hv.y);
    unsafeAtomicAdd(op + 2, c * hv.z);
    unsafeAtomicAdd(op + 3, c * hv.w);
}

extern "C" void kernel_launch(void* const* d_in, const int* in_sizes, int n_in,
                              void* d_out, int out_size, void* d_ws, size_t ws_size,
                              hipStream_t stream) {
    const float* h     = (const float*)d_in[0];
    const float* ini_h = (const float*)d_in[1];
    const float* bef_A = (const float*)d_in[2];
    const float* aft_A = (const float*)d_in[3];
    const float* bef_X = (const float*)d_in[4];
    const int*   src   = (const int*)d_in[5];
    const int*   dst   = (const int*)d_in[6];
    float* out = (float*)d_out;

    const int N = in_sizes[0] / D;      // 100000
    const int E = in_sizes[5];          // 800000
    const int t = 256;

    int NB = (N + NODES_PER_B - 1) >> SH;
    int perB = (NB > 0) ? E / NB : 0;
    int BCAP = ((perB + perB / 4 + 256) + 3) & ~3;   // int4-aligned

    // ws layout (256B aligned regions):
    // gcnt[256] | ovfCnt[64] | ovf int2[OVF_MAX] | cnt_g[N] | ell[N*CAP]
    // | buckets[NB*BCAP] | msgb ushort[N*64]
    size_t o_gcnt = 0;
    size_t o_ovfc = 256 * 4;
    size_t o_ovf  = ((o_ovfc + 64 * 4 + 255) / 256) * 256;
    size_t o_cnt  = o_ovf + (size_t)OVF_MAX * 8;
    size_t o_ell  = ((o_cnt + (size_t)N * 4 + 255) / 256) * 256;
    size_t o_bkt  = ((o_ell + (size_t)N * CAP * 4 + 255) / 256) * 256;
    size_t o_msg  = ((o_bkt + (size_t)NB * BCAP * 4 + 255) / 256) * 256;
    size_t need   = o_msg + (size_t)N * 128;

    if (NB <= 256 && N <= (1 << (31 - SH)) && ws_size >= need) {
        int*  gcnt  = (int*)((char*)d_ws + o_gcnt);
        int*  ovfC  = (int*)((char*)d_ws + o_ovfc);
        int2* ovf   = (int2*)((char*)d_ws + o_ovf);
        int*  cnt_g = (int*)((char*)d_ws + o_cnt);
        int*  ell   = (int*)((char*)d_ws + o_ell);
        int*  bkt   = (int*)((char*)d_ws + o_bkt);
        ushort4* msgb = (ushort4*)((char*)d_ws + o_msg);

        int zeroWords = (int)(o_ovf / 4);   // gcnt + ovfCnt region
        int n16 = N * DV;
        vsgc_msg<<<(n16 + t - 1) / t, t, 0, stream>>>(
            (const float4*)h, aft_A, msgb, (int*)d_ws, zeroWords, n16);

        int nInt4 = (E + 3) >> 2;
        int p1blocks = (nInt4 + 511) / 512;
        p1_scatter<<<p1blocks, 256, 0, stream>>>(
            (const int4*)src, (const int4*)dst, gcnt, bkt, ovf, ovfC, E, NB, BCAP);

        p2_ell<<<NB, 512, 0, stream>>>(bkt, gcnt, ell, cnt_g, ovf, ovfC, N, BCAP);

        long long threadsTotal = (long long)N * 64;
        vsgc_gather_ell<<<(int)((threadsTotal + t - 1) / t), t, 0, stream>>>(
            msgb, (const float4*)h, (const float4*)ini_h, bef_A, bef_X,
            cnt_g, ell, (float4*)out, N);

        vsgc_ovf<<<32, t, 0, stream>>>((const float4*)h, aft_A, bef_A, ovf, ovfC, out);
    } else {
        int n4 = N * DV;
        vsgc_init<<<(n4 + t - 1) / t, t, 0, stream>>>(
            (const float4*)h, (const float4*)ini_h, bef_X, (float4*)out, n4);
        long long total = (long long)E * DV;
        vsgc_edges_atomic<<<(int)((total + t - 1) / t), t, 0, stream>>>(
            (const float4*)h, aft_A, bef_A, src, dst, out, E);
    }
}